// Round 5
// baseline (1038.944 us; speedup 1.0000x reference)
//
#include <hip/hip_runtime.h>

// SemNN — twin-tower masked-pool encoder + classifier.
// B=4096, S=128, D=512, VOCAB=50000, NUM_LABELS=3.
// Confirmed: float inputs bf16 (detector keeps f32 fallback), ids int32,
// masks int-like, OUTPUT f32. ws usage: exactly 16 MB.
//
// Round 13:
//  * r12 post-mortem: container death == GPU hang. The r12 barrier loaded
//    g_gen BEFORE the arrival fetch_add -> stale snapshot race -> premature
//    increments pollute the previous generation's count -> last arriver
//    never sees nb-1 -> infinite spin. r11 (cg::sync, correct-but-160us)
//    proved the fused stage math is right; only the barrier was broken.
//  * FIX: snapshot-free ticket barrier on ONE monotonic counter.
//    a = fetch_add(g_bar,1,acq_rel,agent); target = (a/nb+1)*nb;
//    spin acquire-load until g_bar >= target. Total order on a single
//    atomic => no stale-generation hazard, no reset, replay-safe.
//    Spin is BOUNDED (~50ms) so a logic bug fails the test instead of
//    wedging the GPU.
//  * Everything else unchanged from r11/r12: pool at BW floor (164us,
//    3.2TB/s, FETCH=logical min); GEMM tile body verified (40-u16 LDS rows,
//    B rotate-swizzle, double-buffered, 1 barrier/K-step); fallback
//    separate-launch path if cooperative launch is rejected.

typedef unsigned short u16;
typedef __attribute__((ext_vector_type(8))) short short8;
typedef __attribute__((ext_vector_type(4))) float f32x4;

__device__ __forceinline__ float bfu2f(u16 u) {
    union { unsigned int i; float f; } v;
    v.i = ((unsigned int)u) << 16;
    return v.f;
}

__device__ __forceinline__ u16 f2bfu(float f) {
    union { float f; unsigned int i; } v;
    v.f = f;
    unsigned int x = v.i;
    x += 0x7fffu + ((x >> 16) & 1u);   // RNE
    return (u16)(x >> 16);
}

// tanh(x) = (e^{2x}-1)/(e^{2x}+1) using hw exp2; |x| clamped so e stays
// finite. ~1e-7 rel error, plenty for bf16-rounded outputs.
__device__ __forceinline__ float fast_tanh(float x) {
    float xc = fminf(fmaxf(x, -15.f), 15.f);
    float e = __builtin_amdgcn_exp2f(xc * 2.885390082f);  // 2*log2(e)*x
    return (e - 1.f) / (e + 1.f);
}

// ---------------------------------------------------------------------------
// Grid barrier: monotonic ticket counter, snapshot-free.
// Cooperative launch guarantees all 512 blocks co-resident.
// ---------------------------------------------------------------------------
__device__ unsigned int g_bar = 0;

__device__ __forceinline__ void grid_bar(unsigned int nb) {
    __threadfence();                  // release this block's global writes
    __syncthreads();                  // all waves arrived; vmcnt drained
    if (threadIdx.x == 0) {
        unsigned int a = __hip_atomic_fetch_add(&g_bar, 1u, __ATOMIC_ACQ_REL,
                                                __HIP_MEMORY_SCOPE_AGENT);
        unsigned int target = (a / nb + 1u) * nb;     // end of THIS generation
        // bounded spin: ~50ms worth; never triggers when logic is right,
        // fails the test (instead of wedging the GPU) if it is not.
        for (unsigned int it = 0; it < (1u << 20); ++it) {
            if (__hip_atomic_load(&g_bar, __ATOMIC_ACQUIRE,
                                  __HIP_MEMORY_SCOPE_AGENT) >= target) break;
            __builtin_amdgcn_s_sleep(2);
        }
    }
    __syncthreads();
    __threadfence();                  // acquire: invalidate stale caches
}

// Wave-collective dtype detection; every lane returns flags:
//   bit0: float tensors are bf16 (vs f32); bits2-3: mask type
//   0=int32, 1=byte-bool, 2=bf16, 3=f32
__device__ __forceinline__ int detect_wave(const u16* __restrict__ W,
                                           const unsigned int* __restrict__ m,
                                           int lane)
{
    int cnt = 0;
    int w01 = 1, b01 = 1, lo16 = 0;
    #pragma unroll
    for (int j = lane; j < 256; j += 64) {
        u16 u = W[1024 + 2 * j];
        int e = (u >> 7) & 0xFF;
        cnt += (e >= 0x6A && e <= 0x7E) ? 1 : 0;
        unsigned int v = m[j];
        w01 &= (v <= 1u) ? 1 : 0;
        b01 &= ((v & ~0x01010101u) == 0u) ? 1 : 0;
        lo16 |= ((v & 0xFFFFu) == 0x3F80u) ? 1 : 0;
    }
    #pragma unroll
    for (int off = 32; off > 0; off >>= 1) {
        cnt  += __shfl_down(cnt, off);
        w01  &= __shfl_down(w01, off);
        b01  &= __shfl_down(b01, off);
        lo16 |= __shfl_down(lo16, off);
    }
    int mtype;
    if (w01)        mtype = 0;
    else if (b01)   mtype = 1;
    else if (lo16)  mtype = 2;
    else            mtype = 3;
    int fl = ((cnt >= 128) ? 1 : 0) | (mtype << 2);
    return __shfl(fl, 0);
}

__device__ __forceinline__ int mask_nonzero(const void* __restrict__ msk,
                                            int idx, int mtype)
{
    switch (mtype) {
        case 0:  return ((const int*)msk)[idx] != 0;
        case 1:  return ((const unsigned char*)msk)[idx] != 0;
        case 2:  return ((const u16*)msk)[idx] != 0;
        default: return ((const unsigned int*)msk)[idx] != 0u;
    }
}

// ---------------------------------------------------------------------------
// Kernel 1: embedding gather + masked sum-pool for BOTH sides -> P [8192,512].
// 8192 blocks (one per output row; row>=4096 is side b), 128 threads = 2
// waves; lane owns 16B of the 1KB row; waves split tokens; LDS combine.
// UNCHANGED: measured 164us / 3.2 TB/s / FETCH = logical min.
// ---------------------------------------------------------------------------
__global__ __launch_bounds__(128) void pool_kernel(
    const int* __restrict__ ids_a, const int* __restrict__ ids_b,
    const void* __restrict__ mska, const void* __restrict__ mskb,
    const void* __restrict__ W, u16* __restrict__ P,
    const unsigned int* __restrict__ Mdet)
{
    __shared__ int s_ids[128];
    __shared__ int s_cnt;
    __shared__ int s_flags;
    __shared__ float sP[512];
    const int t = threadIdx.x;
    const int w = t >> 6;
    const int lane = t & 63;

    if (t == 0) s_cnt = 0;
    if (t < 64) {
        int fl = detect_wave((const u16*)W, Mdet, t);
        if (t == 0) s_flags = fl;
    }
    __syncthreads();
    const int  flags = s_flags;
    const bool isbf  = (flags & 1) != 0;
    const int  mtype = (flags >> 2) & 3;

    const int row = blockIdx.x;            // 0..8191
    const int r   = row & 4095;
    const int* __restrict__ ids = (row < 4096) ? ids_a : ids_b;
    const void* __restrict__ msk = (row < 4096) ? mska : mskb;

    int id = ids[r * 128 + t];
    int mk = mask_nonzero(msk, r * 128 + t, mtype);
    if (mk) {
        int idx = atomicAdd(&s_cnt, 1);
        s_ids[idx] = id;
    }
    __syncthreads();
    const int cnt = s_cnt;

    float acc[8] = {};
    if (isbf) {
        const u16* Wb = (const u16*)W;
        int j = w;
        for (; j + 6 < cnt; j += 8) {
            union { uint4 v; u16 s[8]; } r0, r1, r2, r3;
            r0.v = *(const uint4*)(Wb + (size_t)s_ids[j + 0] * 512 + lane * 8);
            r1.v = *(const uint4*)(Wb + (size_t)s_ids[j + 2] * 512 + lane * 8);
            r2.v = *(const uint4*)(Wb + (size_t)s_ids[j + 4] * 512 + lane * 8);
            r3.v = *(const uint4*)(Wb + (size_t)s_ids[j + 6] * 512 + lane * 8);
            #pragma unroll
            for (int i = 0; i < 8; ++i)
                acc[i] += bfu2f(r0.s[i]) + bfu2f(r1.s[i]) +
                          bfu2f(r2.s[i]) + bfu2f(r3.s[i]);
        }
        for (; j < cnt; j += 2) {
            union { uint4 v; u16 s[8]; } rr;
            rr.v = *(const uint4*)(Wb + (size_t)s_ids[j] * 512 + lane * 8);
            #pragma unroll
            for (int i = 0; i < 8; ++i) acc[i] += bfu2f(rr.s[i]);
        }
    } else {
        const float* Wf = (const float*)W;
        for (int j = w; j < cnt; j += 2) {
            const float* rp = Wf + (size_t)s_ids[j] * 512 + lane * 8;
            float4 a = *(const float4*)(rp + 0);
            float4 b = *(const float4*)(rp + 4);
            acc[0] += a.x; acc[1] += a.y; acc[2] += a.z; acc[3] += a.w;
            acc[4] += b.x; acc[5] += b.y; acc[6] += b.z; acc[7] += b.w;
        }
    }

    if (w == 0) {
        #pragma unroll
        for (int i = 0; i < 8; ++i) sP[lane * 8 + i] = acc[i];
    }
    __syncthreads();
    if (w == 1) {
        union { uint4 v; u16 s[8]; } o;
        #pragma unroll
        for (int i = 0; i < 8; ++i)
            o.s[i] = f2bfu(acc[i] + sP[lane * 8 + i]);
        *(uint4*)(P + (size_t)row * 512 + lane * 8) = o.v;
    }
}

// ---------------------------------------------------------------------------
// GEMM tile: bf16 MFMA + bias + tanh.  C[m0:+128, n0:+64] over K.
// N fixed at 512. 512 threads (8 waves, 4x2 of 32x32 wave tiles), BK=32,
// double-buffered LDS, one barrier per K-step. Verified index math:
// 40-u16 LDS rows, B rotate-swizzle, C/D layout col=lane&15 row=kq*4+r.
// ---------------------------------------------------------------------------
template<bool ISBF>
__device__ __forceinline__ void gemm_tile(
    const u16* __restrict__ A, const u16* __restrict__ A2, const int K1,
    const void* __restrict__ Bv, const void* __restrict__ biasv,
    u16* __restrict__ C, const int K, const int m0, const int n0,
    u16* __restrict__ As0, u16* __restrict__ Bs0)
{
    const int tid  = threadIdx.x;          // 0..511
    const int lane = tid & 63;
    const int wid = tid >> 6;              // 0..7
    const int wm  = (wid & 3) * 32;
    const int wn  = (wid >> 2) * 32;
    const int ar = tid >> 2;               // 0..127, one uint4 of A per thread
    const int ak = (tid & 3) * 8;
    const int bk = tid >> 3;               // B staging: threads 0..255 only
    const int jn = tid & 7;
    const int nb = jn * 8;
    const int bofs = (((bk >> 3) + jn) & 3) * 8 + (bk & 7);
    const int lm = lane & 15;
    const int kq = lane >> 4;
    const int kc = kq * 8;

    const u16*   Bb = (const u16*)Bv;
    const float* Bf = (const float*)Bv;

    f32x4 acc[2][2];
    #pragma unroll
    for (int i = 0; i < 2; ++i)
        #pragma unroll
        for (int j = 0; j < 2; ++j)
            acc[i][j] = (f32x4){0.f, 0.f, 0.f, 0.f};

    uint4 ra;
    uint4 rbb;
    float4 rf0, rf1;

    // fetch(k0): coalesced A (16B/lane, 4 lanes/row) + B (16B/lane, 8/row)
    #define FETCH(k0)                                                         \
    {                                                                         \
        const int kg = (k0) + ak;                                             \
        const u16* base = (kg < K1) ? (A + kg) : (A2 + (kg - K1));            \
        ra = *(const uint4*)(base + (size_t)(m0 + ar) * 512);                 \
        if (tid < 256) {                                                      \
            if constexpr (ISBF) {                                             \
                rbb = *(const uint4*)(Bb + (size_t)((k0) + bk) * 512 + n0 + nb);\
            } else {                                                          \
                const float* Bp = Bf + (size_t)((k0) + bk) * 512 + n0 + nb;   \
                rf0 = *(const float4*)(Bp + 0);                               \
                rf1 = *(const float4*)(Bp + 4);                               \
            }                                                                 \
        }                                                                     \
    }

    // store regs -> LDS buffer pp (A: one b128; B: 8 swizzled b16 stores)
    #define STORE(pp)                                                         \
    {                                                                         \
        *(uint4*)&As0[(pp) * 5120 + ar * 40 + ak] = ra;                       \
        if (tid < 256) {                                                      \
            u16 bvals[8];                                                     \
            if constexpr (ISBF) {                                             \
                union { uint4 v; u16 s[8]; } ub; ub.v = rbb;                  \
                _Pragma("unroll")                                             \
                for (int i = 0; i < 8; ++i) bvals[i] = ub.s[i];               \
            } else {                                                          \
                bvals[0] = f2bfu(rf0.x); bvals[1] = f2bfu(rf0.y);             \
                bvals[2] = f2bfu(rf0.z); bvals[3] = f2bfu(rf0.w);             \
                bvals[4] = f2bfu(rf1.x); bvals[5] = f2bfu(rf1.y);             \
                bvals[6] = f2bfu(rf1.z); bvals[7] = f2bfu(rf1.w);             \
            }                                                                 \
            _Pragma("unroll")                                                 \
            for (int i = 0; i < 8; ++i)                                       \
                Bs0[(pp) * 2560 + (nb + i) * 40 + bofs] = bvals[i];           \
        }                                                                     \
    }

    FETCH(0)
    STORE(0)
    FETCH(32)                              // K >= 64 always (512 or 1024)
    __syncthreads();

    int p = 0;
    for (int k0 = 0; k0 < K; k0 += 32) {
        if (k0 + 32 < K) {
            STORE(p ^ 1)                   // tile k0+32 (fetched last iter)
            if (k0 + 64 < K) FETCH(k0 + 64)  // in flight across this compute
        }

        const u16* Ap = As0 + p * 5120;
        const u16* Bp2 = Bs0 + p * 2560;
        short8 af[2], bf[2];
        #pragma unroll
        for (int i = 0; i < 2; ++i)
            af[i] = *(const short8*)&Ap[(wm + i * 16 + lm) * 40 + kc];
        #pragma unroll
        for (int j = 0; j < 2; ++j) {
            const int n = wn + j * 16 + lm;
            const int ch = ((kq + (n >> 3)) & 3) * 8;
            bf[j] = *(const short8*)&Bp2[n * 40 + ch];
        }
        #pragma unroll
        for (int i = 0; i < 2; ++i)
            #pragma unroll
            for (int j = 0; j < 2; ++j)
                acc[i][j] = __builtin_amdgcn_mfma_f32_16x16x32_bf16(
                    af[i], bf[j], acc[i][j], 0, 0, 0);

        if (k0 + 32 < K) __syncthreads();  // one barrier per K-step
        p ^= 1;
    }
    #undef FETCH
    #undef STORE

    // epilogue: bias + tanh + bf16 store
    #pragma unroll
    for (int j = 0; j < 2; ++j) {
        const int n = n0 + wn + j * 16 + lm;
        const float bsv = ISBF ? bfu2f(((const u16*)biasv)[n])
                               : ((const float*)biasv)[n];
        #pragma unroll
        for (int i = 0; i < 2; ++i) {
            #pragma unroll
            for (int r = 0; r < 4; ++r) {
                const int m = m0 + wm + i * 16 + kq * 4 + r;
                C[(size_t)m * 512 + n] = f2bfu(fast_tanh(acc[i][j][r] + bsv));
            }
        }
    }
}

// ---------------------------------------------------------------------------
// Fused encoder: GEMM1 -> GEMM2 -> GEMM3 -> logits in ONE cooperative
// dispatch, 512 blocks x 512 threads (exactly 2 blocks/CU co-resident).
// 3 custom grid barriers; every block reaches all 3 (uniform control flow).
// ---------------------------------------------------------------------------
template<bool ISBF>
__device__ __forceinline__ void fused_body(
    const void* __restrict__ w1, const void* __restrict__ b1,
    const void* __restrict__ w2, const void* __restrict__ b2,
    const void* __restrict__ cw1, const void* __restrict__ cb1,
    const void* __restrict__ cw2, const void* __restrict__ cb2,
    u16* __restrict__ buf0, u16* __restrict__ buf1,
    float* __restrict__ out, u16* As, u16* Bs)
{
    const int bid = blockIdx.x;
    const int tid = threadIdx.x;
    const int m0 = (bid & 63) * 128;
    const int n0 = (bid >> 6) * 64;

    // Stage 1+2: X1 = tanh(P @ w1 + b1), X2 = tanh(X1 @ w2 + b2)
    const u16* src = buf0;
    u16*       dst = buf1;
    #pragma unroll 1
    for (int s = 0; s < 2; ++s) {
        const void* ww = s ? w2 : w1;
        const void* bb = s ? b2 : b1;
        gemm_tile<ISBF>(src, src, 512, ww, bb, dst, 512, m0, n0, As, Bs);
        grid_bar(512u);
        const u16* t = src; src = dst; dst = (u16*)t;
    }
    // now: X2 in buf0, buf1 free

    // Stage 3: H = tanh([va | vb] @ cw1 + cb1) -> buf1  (256 active blocks)
    if (bid < 256)
        gemm_tile<ISBF>(buf0, buf0 + (size_t)4096 * 512, 512, cw1, cb1,
                        buf1, 1024, (bid & 31) * 128, (bid >> 5) * 64, As, Bs);
    grid_bar(512u);

    // Stage 4: logits. 8 rows per block (wave w handles row bid*8+w).
    const int lane = tid & 63;
    const int m = bid * 8 + (tid >> 6);    // 0..4095
    union { uint4 v; u16 s[8]; } h;
    h.v = *(const uint4*)(buf1 + (size_t)m * 512 + lane * 8);

    float a0 = 0.f, a1 = 0.f, a2 = 0.f;
    #pragma unroll
    for (int i = 0; i < 8; ++i) {
        const int k = lane * 8 + i;
        float x = bfu2f(h.s[i]);
        float v0, v1, v2;
        if constexpr (ISBF) {
            const u16* Wb = (const u16*)cw2;
            v0 = bfu2f(Wb[k * 3 + 0]); v1 = bfu2f(Wb[k * 3 + 1]); v2 = bfu2f(Wb[k * 3 + 2]);
        } else {
            const float* Wf = (const float*)cw2;
            v0 = Wf[k * 3 + 0]; v1 = Wf[k * 3 + 1]; v2 = Wf[k * 3 + 2];
        }
        a0 += x * v0; a1 += x * v1; a2 += x * v2;
    }
    #pragma unroll
    for (int off = 32; off > 0; off >>= 1) {
        a0 += __shfl_down(a0, off);
        a1 += __shfl_down(a1, off);
        a2 += __shfl_down(a2, off);
    }
    if (lane == 0) {
        float c0, c1, c2;
        if constexpr (ISBF) {
            const u16* bb = (const u16*)cb2;
            c0 = bfu2f(bb[0]); c1 = bfu2f(bb[1]); c2 = bfu2f(bb[2]);
        } else {
            const float* bf = (const float*)cb2;
            c0 = bf[0]; c1 = bf[1]; c2 = bf[2];
        }
        out[m * 3 + 0] = a0 + c0;
        out[m * 3 + 1] = a1 + c1;
        out[m * 3 + 2] = a2 + c2;
    }
}

__global__ __launch_bounds__(512, 4) void fused_enc(
    const void* __restrict__ w1, const void* __restrict__ b1,
    const void* __restrict__ w2, const void* __restrict__ b2,
    const void* __restrict__ cw1, const void* __restrict__ cb1,
    const void* __restrict__ cw2, const void* __restrict__ cb2,
    u16* __restrict__ buf0, u16* __restrict__ buf1,
    float* __restrict__ out,
    const u16* __restrict__ Wdet, const unsigned int* __restrict__ Mdet)
{
    __shared__ __align__(16) u16 As[2 * 128 * 40];
    __shared__ __align__(16) u16 Bs[2 * 64 * 40];
    __shared__ int s_flags;

    if (threadIdx.x < 64) {
        int fl = detect_wave(Wdet, Mdet, threadIdx.x);
        if (threadIdx.x == 0) s_flags = fl;
    }
    __syncthreads();
    // data-uniform across the grid -> every block takes the same branch,
    // so all blocks reach the same 3 grid barriers.
    if (s_flags & 1)
        fused_body<true >(w1, b1, w2, b2, cw1, cb1, cw2, cb2, buf0, buf1, out, As, Bs);
    else
        fused_body<false>(w1, b1, w2, b2, cw1, cb1, cw2, cb2, buf0, buf1, out, As, Bs);
}

// ---------------------------------------------------------------------------
// Fallback path (separate launches, round-10 structure) in case the
// cooperative launch is rejected by the runtime/graph capture.
// ---------------------------------------------------------------------------
__global__ __launch_bounds__(512, 4) void gemm_mfma(
    const u16* __restrict__ A, const u16* __restrict__ A2, int K1,
    const void* __restrict__ B, const void* __restrict__ bias,
    u16* __restrict__ C, int K,
    const u16* __restrict__ Wdet, const unsigned int* __restrict__ Mdet)
{
    __shared__ __align__(16) u16 As[2 * 128 * 40];
    __shared__ __align__(16) u16 Bs[2 * 64 * 40];
    __shared__ int s_flags;

    if (threadIdx.x < 64) {
        int fl = detect_wave(Wdet, Mdet, threadIdx.x);
        if (threadIdx.x == 0) s_flags = fl;
    }
    __syncthreads();
    const int m0 = blockIdx.x * 128;
    const int n0 = blockIdx.y * 64;
    if (s_flags & 1) gemm_tile<true >(A, A2, K1, B, bias, C, K, m0, n0, As, Bs);
    else             gemm_tile<false>(A, A2, K1, B, bias, C, K, m0, n0, As, Bs);
}

__global__ __launch_bounds__(64) void logits_kernel(
    const u16* __restrict__ H, const void* __restrict__ W2,
    const void* __restrict__ b2, float* __restrict__ out,
    const u16* __restrict__ Wdet, const unsigned int* __restrict__ Mdet)
{
    const int lane = threadIdx.x;
    const int fl = detect_wave(Wdet, Mdet, lane);
    const bool isbf = (fl & 1) != 0;

    const int m = blockIdx.x;
    union { uint4 v; u16 s[8]; } h;
    h.v = *(const uint4*)(H + (size_t)m * 512 + lane * 8);

    float a0 = 0.f, a1 = 0.f, a2 = 0.f;
    #pragma unroll
    for (int i = 0; i < 8; ++i) {
        const int k = lane * 8 + i;
        float x = bfu2f(h.s[i]);
        float w0, w1, w2;
        if (isbf) {
            const u16* Wb = (const u16*)W2;
            w0 = bfu2f(Wb[k * 3 + 0]); w1 = bfu2f(Wb[k * 3 + 1]); w2 = bfu2f(Wb[k * 3 + 2]);
        } else {
            const float* Wf = (const float*)W2;
            w0 = Wf[k * 3 + 0]; w1 = Wf[k * 3 + 1]; w2 = Wf[k * 3 + 2];
        }
        a0 += x * w0; a1 += x * w1; a2 += x * w2;
    }
    #pragma unroll
    for (int off = 32; off > 0; off >>= 1) {
        a0 += __shfl_down(a0, off);
        a1 += __shfl_down(a1, off);
        a2 += __shfl_down(a2, off);
    }
    if (lane == 0) {
        float b0, b1, b2v;
        if (isbf) {
            const u16* bb = (const u16*)b2;
            b0 = bfu2f(bb[0]); b1 = bfu2f(bb[1]); b2v = bfu2f(bb[2]);
        } else {
            const float* bf = (const float*)b2;
            b0 = bf[0]; b1 = bf[1]; b2v = bf[2];
        }
        out[m * 3 + 0] = a0 + b0;
        out[m * 3 + 1] = a1 + b1;
        out[m * 3 + 2] = a2 + b2v;
    }
}

// ---------------------------------------------------------------------------
extern "C" void kernel_launch(void* const* d_in, const int* in_sizes, int n_in,
                              void* d_out, int out_size, void* d_ws, size_t ws_size,
                              hipStream_t stream)
{
    const int* ids_a  = (const int*)d_in[0];
    const int* ids_b  = (const int*)d_in[1];
    const void* mask_a = d_in[2];
    const void* mask_b = d_in[3];
    const void* W_emb  = d_in[4];
    const void* enc_w1 = d_in[5];
    const void* enc_b1 = d_in[6];
    const void* enc_w2 = d_in[7];
    const void* enc_b2 = d_in[8];
    const void* cls_w1 = d_in[9];
    const void* cls_b1 = d_in[10];
    const void* cls_w2 = d_in[11];
    const void* cls_b2 = d_in[12];

    const u16* Wdet = (const u16*)W_emb;
    const unsigned int* Mdet = (const unsigned int*)mask_a;

    u16* buf0 = (u16*)d_ws;                          // 8192*512 bf16 = 8 MB
    u16* buf1 = buf0 + (size_t)8192 * 512;           // 8 MB  (total 16 MB)
    float* outp = (float*)d_out;

    // pooled -> buf0 (rows 0..4095 side a, 4096..8191 side b), one dispatch
    pool_kernel<<<8192, 128, 0, stream>>>(ids_a, ids_b, mask_a, mask_b,
                                          W_emb, buf0, Mdet);

    // one cooperative dispatch for GEMM1+GEMM2+GEMM3+logits
    void* args[13] = {
        (void*)&enc_w1, (void*)&enc_b1, (void*)&enc_w2, (void*)&enc_b2,
        (void*)&cls_w1, (void*)&cls_b1, (void*)&cls_w2, (void*)&cls_b2,
        (void*)&buf0,   (void*)&buf1,   (void*)&outp,
        (void*)&Wdet,   (void*)&Mdet
    };
    hipError_t err = hipLaunchCooperativeKernel(
        (const void*)fused_enc, dim3(512, 1, 1), dim3(512, 1, 1),
        args, 0, stream);

    if (err != hipSuccess) {
        // fallback: round-10 separate launches (same math)
        gemm_mfma<<<dim3(64, 8), 512, 0, stream>>>(
            buf0, buf0, 512, enc_w1, enc_b1, buf1, 512, Wdet, Mdet);
        gemm_mfma<<<dim3(64, 8), 512, 0, stream>>>(
            buf1, buf1, 512, enc_w2, enc_b2, buf0, 512, Wdet, Mdet);
        gemm_mfma<<<dim3(32, 8), 512, 0, stream>>>(
            buf0, buf0 + (size_t)4096 * 512, 512, cls_w1, cls_b1, buf1, 1024, Wdet, Mdet);
        logits_kernel<<<4096, 64, 0, stream>>>(buf1, cls_w2, cls_b2, outp, Wdet, Mdet);
    }
}

// Round 6
// 409.457 us; speedup vs baseline: 2.5374x; 2.5374x over previous
//
#include <hip/hip_runtime.h>

// SemNN — twin-tower masked-pool encoder + classifier.
// B=4096, S=128, D=512, VOCAB=50000, NUM_LABELS=3.
// Confirmed: float inputs bf16 (detector keeps f32 fallback), ids int32,
// masks int-like, OUTPUT f32. ws usage: 16 MB (buf1 now unused).
//
// Round 14:
//  * r11/r13 post-mortem: grid-wide sync INSIDE a kernel costs 160-230us per
//    barrier on MI355X (cg::sync 160us; hand-rolled ticket barrier 228us —
//    the agent-scope fences flush/invalidate the 8 non-coherent per-XCD L2s
//    from every thread). A dispatch boundary (~20us) is CHEAPER. Abandon
//    single-kernel fusion. Extracted fact: GEMM1+2+3+logits real work is
//    only ~40us total.
//  * FIX: remove sync boundaries that need no grid sync at all:
//    - enc12: GEMM1+GEMM2 fused per-row-block. Block owns 32 rows; P
//      A-frags for K=512 in 64 VGPRs; X1 round-trips through a 4KB LDS
//      shuffle into phase-2 A-frags (64 VGPRs); X2 written in place.
//      B-staging: verified r10 chunk-rotate swizzle generalized to BK=128
//      (16 chunks). No X1 global round-trip (saves 16MB traffic).
//    - gemm3_logits: logits computed in GEMM3's epilogue (H never stored):
//      per-thread 24 partial logits, shfl_xor reduce over lm lanes, f32
//      atomicAdd into memset-zeroed d_out; bias added once (nb8==0,wn==0).
//  * Dispatches: 5 -> 3 (+memset). No spins/fences — nothing can hang.
//  * Pool unchanged (164us, 3.2TB/s, FETCH = logical min).

typedef unsigned short u16;
typedef __attribute__((ext_vector_type(8))) short short8;
typedef __attribute__((ext_vector_type(4))) float f32x4;

__device__ __forceinline__ float bfu2f(u16 u) {
    union { unsigned int i; float f; } v;
    v.i = ((unsigned int)u) << 16;
    return v.f;
}

__device__ __forceinline__ u16 f2bfu(float f) {
    union { float f; unsigned int i; } v;
    v.f = f;
    unsigned int x = v.i;
    x += 0x7fffu + ((x >> 16) & 1u);   // RNE
    return (u16)(x >> 16);
}

// tanh(x) = (e^{2x}-1)/(e^{2x}+1) using hw exp2; |x| clamped so e stays
// finite. ~1e-7 rel error, plenty for bf16-rounded outputs.
__device__ __forceinline__ float fast_tanh(float x) {
    float xc = fminf(fmaxf(x, -15.f), 15.f);
    float e = __builtin_amdgcn_exp2f(xc * 2.885390082f);  // 2*log2(e)*x
    return (e - 1.f) / (e + 1.f);
}

// Wave-collective dtype detection; every lane returns flags:
//   bit0: float tensors are bf16 (vs f32); bits2-3: mask type
//   0=int32, 1=byte-bool, 2=bf16, 3=f32
__device__ __forceinline__ int detect_wave(const u16* __restrict__ W,
                                           const unsigned int* __restrict__ m,
                                           int lane)
{
    int cnt = 0;
    int w01 = 1, b01 = 1, lo16 = 0;
    #pragma unroll
    for (int j = lane; j < 256; j += 64) {
        u16 u = W[1024 + 2 * j];
        int e = (u >> 7) & 0xFF;
        cnt += (e >= 0x6A && e <= 0x7E) ? 1 : 0;
        unsigned int v = m[j];
        w01 &= (v <= 1u) ? 1 : 0;
        b01 &= ((v & ~0x01010101u) == 0u) ? 1 : 0;
        lo16 |= ((v & 0xFFFFu) == 0x3F80u) ? 1 : 0;
    }
    #pragma unroll
    for (int off = 32; off > 0; off >>= 1) {
        cnt  += __shfl_down(cnt, off);
        w01  &= __shfl_down(w01, off);
        b01  &= __shfl_down(b01, off);
        lo16 |= __shfl_down(lo16, off);
    }
    int mtype;
    if (w01)        mtype = 0;
    else if (b01)   mtype = 1;
    else if (lo16)  mtype = 2;
    else            mtype = 3;
    int fl = ((cnt >= 128) ? 1 : 0) | (mtype << 2);
    return __shfl(fl, 0);
}

__device__ __forceinline__ int mask_nonzero(const void* __restrict__ msk,
                                            int idx, int mtype)
{
    switch (mtype) {
        case 0:  return ((const int*)msk)[idx] != 0;
        case 1:  return ((const unsigned char*)msk)[idx] != 0;
        case 2:  return ((const u16*)msk)[idx] != 0;
        default: return ((const unsigned int*)msk)[idx] != 0u;
    }
}

// ---------------------------------------------------------------------------
// Kernel 1: embedding gather + masked sum-pool for BOTH sides -> P [8192,512].
// UNCHANGED: measured 164us / 3.2 TB/s / FETCH = logical min.
// ---------------------------------------------------------------------------
__global__ __launch_bounds__(128) void pool_kernel(
    const int* __restrict__ ids_a, const int* __restrict__ ids_b,
    const void* __restrict__ mska, const void* __restrict__ mskb,
    const void* __restrict__ W, u16* __restrict__ P,
    const unsigned int* __restrict__ Mdet)
{
    __shared__ int s_ids[128];
    __shared__ int s_cnt;
    __shared__ int s_flags;
    __shared__ float sP[512];
    const int t = threadIdx.x;
    const int w = t >> 6;
    const int lane = t & 63;

    if (t == 0) s_cnt = 0;
    if (t < 64) {
        int fl = detect_wave((const u16*)W, Mdet, t);
        if (t == 0) s_flags = fl;
    }
    __syncthreads();
    const int  flags = s_flags;
    const bool isbf  = (flags & 1) != 0;
    const int  mtype = (flags >> 2) & 3;

    const int row = blockIdx.x;            // 0..8191
    const int r   = row & 4095;
    const int* __restrict__ ids = (row < 4096) ? ids_a : ids_b;
    const void* __restrict__ msk = (row < 4096) ? mska : mskb;

    int id = ids[r * 128 + t];
    int mk = mask_nonzero(msk, r * 128 + t, mtype);
    if (mk) {
        int idx = atomicAdd(&s_cnt, 1);
        s_ids[idx] = id;
    }
    __syncthreads();
    const int cnt = s_cnt;

    float acc[8] = {};
    if (isbf) {
        const u16* Wb = (const u16*)W;
        int j = w;
        for (; j + 6 < cnt; j += 8) {
            union { uint4 v; u16 s[8]; } r0, r1, r2, r3;
            r0.v = *(const uint4*)(Wb + (size_t)s_ids[j + 0] * 512 + lane * 8);
            r1.v = *(const uint4*)(Wb + (size_t)s_ids[j + 2] * 512 + lane * 8);
            r2.v = *(const uint4*)(Wb + (size_t)s_ids[j + 4] * 512 + lane * 8);
            r3.v = *(const uint4*)(Wb + (size_t)s_ids[j + 6] * 512 + lane * 8);
            #pragma unroll
            for (int i = 0; i < 8; ++i)
                acc[i] += bfu2f(r0.s[i]) + bfu2f(r1.s[i]) +
                          bfu2f(r2.s[i]) + bfu2f(r3.s[i]);
        }
        for (; j < cnt; j += 2) {
            union { uint4 v; u16 s[8]; } rr;
            rr.v = *(const uint4*)(Wb + (size_t)s_ids[j] * 512 + lane * 8);
            #pragma unroll
            for (int i = 0; i < 8; ++i) acc[i] += bfu2f(rr.s[i]);
        }
    } else {
        const float* Wf = (const float*)W;
        for (int j = w; j < cnt; j += 2) {
            const float* rp = Wf + (size_t)s_ids[j] * 512 + lane * 8;
            float4 a = *(const float4*)(rp + 0);
            float4 b = *(const float4*)(rp + 4);
            acc[0] += a.x; acc[1] += a.y; acc[2] += a.z; acc[3] += a.w;
            acc[4] += b.x; acc[5] += b.y; acc[6] += b.z; acc[7] += b.w;
        }
    }

    if (w == 0) {
        #pragma unroll
        for (int i = 0; i < 8; ++i) sP[lane * 8 + i] = acc[i];
    }
    __syncthreads();
    if (w == 1) {
        union { uint4 v; u16 s[8]; } o;
        #pragma unroll
        for (int i = 0; i < 8; ++i)
            o.s[i] = f2bfu(acc[i] + sP[lane * 8 + i]);
        *(uint4*)(P + (size_t)row * 512 + lane * 8) = o.v;
    }
}

// ---------------------------------------------------------------------------
// Kernel 2: enc12 — X2 = tanh(tanh(P@w1+b1)@w2+b2), fused, no grid sync.
// 256 blocks x 512 threads; block owns rows R0=bid*32..+32 end-to-end.
// 8 waves as 2m x 4n, wave tile 16x16. A-frags (K=512) in 64 VGPRs.
// B staged BK=128, dbuf, 16-chunk rotate swizzle (r10's scheme generalized).
// X1 C-frags -> 4KB LDS shuffle -> phase-2 A-frags (64 VGPRs).
// X2 written in place over P (block touches only its own rows).
// ---------------------------------------------------------------------------
template<bool ISBF>
__device__ __forceinline__ void enc12_body(
    u16* __restrict__ P,
    const void* __restrict__ w1v, const void* __restrict__ b1v,
    const void* __restrict__ w2v, const void* __restrict__ b2v,
    u16* __restrict__ Bs, u16* __restrict__ Xbuf)
{
    const int tid  = threadIdx.x;          // 0..511
    const int lane = tid & 63;
    const int wid  = tid >> 6;             // 0..7
    const int wm   = (wid & 1) * 16;       // 2 m-groups (32 rows)
    const int wn   = (wid >> 1) * 16;      // 4 n-groups (64 cols)
    const int lm   = lane & 15;
    const int kq   = lane >> 4;
    const int kc   = kq * 8;
    const int R0   = blockIdx.x * 32;

    const int bk = tid >> 3;               // 0..63 (k-rows; +64 for 2nd half)
    const int jn = tid & 7;
    const int nb = jn * 8;

    const u16*   b1b = (const u16*)b1v; const float* b1f = (const float*)b1v;
    const u16*   b2b = (const u16*)b2v; const float* b2f = (const float*)b2v;

    // phase-1 A-frags: P rows R0+wm+lm, all K=512 (16 x short8 = 64 VGPR)
    short8 af[16];
    {
        const u16* arow = P + (size_t)(R0 + wm + lm) * 512 + kc;
        #pragma unroll
        for (int s = 0; s < 16; ++s)
            af[s] = *(const short8*)(arow + s * 32);
    }
    short8 af2[16];                        // phase-2 A-frags (filled in ph1)

    const u16* Wb; const float* Wf;
    uint4 rb0, rb1;
    float4 rf00, rf01, rf10, rf11;

// fetch one BK=128 k-chunk of the 64-col weight tile (coalesced, 16B/lane)
#define FETCHW(k0, n0)                                                        \
    {                                                                         \
        const int kr0 = (k0) + bk;                                            \
        const int kr1 = (k0) + bk + 64;                                       \
        if constexpr (ISBF) {                                                 \
            rb0 = *(const uint4*)(Wb + (size_t)kr0 * 512 + (n0) + nb);        \
            rb1 = *(const uint4*)(Wb + (size_t)kr1 * 512 + (n0) + nb);        \
        } else {                                                              \
            const float* p0_ = Wf + (size_t)kr0 * 512 + (n0) + nb;            \
            const float* p1_ = Wf + (size_t)kr1 * 512 + (n0) + nb;            \
            rf00 = *(const float4*)p0_; rf01 = *(const float4*)(p0_ + 4);     \
            rf10 = *(const float4*)p1_; rf11 = *(const float4*)(p1_ + 4);     \
        }                                                                     \
    }

// store regs -> Bs[pp]: row n (136 u16 = 16 chunks of 8 + pad), chunk-rotate
// swizzle c=((k>>3)+n/8)&15 (r10's verified scheme, 4->16 chunks)
#define STOREW(pp)                                                            \
    {                                                                         \
        u16 bv0[8], bv1[8];                                                   \
        if constexpr (ISBF) {                                                 \
            union { uint4 v; u16 s[8]; } u0_, u1_;                            \
            u0_.v = rb0; u1_.v = rb1;                                         \
            _Pragma("unroll")                                                 \
            for (int i = 0; i < 8; ++i) { bv0[i] = u0_.s[i]; bv1[i] = u1_.s[i]; } \
        } else {                                                              \
            bv0[0]=f2bfu(rf00.x); bv0[1]=f2bfu(rf00.y);                       \
            bv0[2]=f2bfu(rf00.z); bv0[3]=f2bfu(rf00.w);                       \
            bv0[4]=f2bfu(rf01.x); bv0[5]=f2bfu(rf01.y);                       \
            bv0[6]=f2bfu(rf01.z); bv0[7]=f2bfu(rf01.w);                       \
            bv1[0]=f2bfu(rf10.x); bv1[1]=f2bfu(rf10.y);                       \
            bv1[2]=f2bfu(rf10.z); bv1[3]=f2bfu(rf10.w);                       \
            bv1[4]=f2bfu(rf11.x); bv1[5]=f2bfu(rf11.y);                       \
            bv1[6]=f2bfu(rf11.z); bv1[7]=f2bfu(rf11.w);                       \
        }                                                                     \
        const int o0_ = ((((bk >> 3) + jn) & 15)) * 8 + (bk & 7);             \
        const int o1_ = ((((bk >> 3) + 8 + jn) & 15)) * 8 + (bk & 7);         \
        _Pragma("unroll")                                                     \
        for (int i = 0; i < 8; ++i) {                                         \
            Bs[(pp) * 8704 + (nb + i) * 136 + o0_] = bv0[i];                  \
            Bs[(pp) * 8704 + (nb + i) * 136 + o1_] = bv1[i];                  \
        }                                                                     \
    }

// K=512 loop: 4 BK=128 chunks, dbuf, 1 barrier per chunk. afin indexed
// statically (kb fully unrolled).
#define KLOOP(afin)                                                           \
    FETCHW(0, n0) STOREW(0) FETCHW(128, n0)                                   \
    __syncthreads();                                                          \
    _Pragma("unroll")                                                         \
    for (int kb = 0; kb < 4; ++kb) {                                          \
        const int p_ = kb & 1;                                                \
        if (kb < 3) { STOREW(p_ ^ 1) if (kb < 2) FETCHW((kb + 2) * 128, n0) } \
        _Pragma("unroll")                                                     \
        for (int s = 0; s < 4; ++s) {                                         \
            const int n_ = wn + lm;                                           \
            const int ch = (((s * 4 + kq) + (n_ >> 3)) & 15) * 8;             \
            short8 bf = *(const short8*)&Bs[p_ * 8704 + n_ * 136 + ch];       \
            acc = __builtin_amdgcn_mfma_f32_16x16x32_bf16(afin[kb * 4 + s],   \
                                                          bf, acc, 0, 0, 0);  \
        }                                                                     \
        if (kb < 3) __syncthreads();                                          \
    }

    // ---- phase 1: X1 tiles -> LDS shuffle -> af2 (t unrolled: af2 static)
    Wb = (const u16*)w1v; Wf = (const float*)w1v;
    #pragma unroll
    for (int t = 0; t < 8; ++t) {
        const int n0 = t * 64;
        f32x4 acc = (f32x4){0.f, 0.f, 0.f, 0.f};
        KLOOP(af)
        // epilogue: tanh -> Xbuf (C-layout rows kq*4+r, col wn+lm)
        const int   ncol = n0 + wn + lm;
        const float bia  = ISBF ? bfu2f(b1b[ncol]) : b1f[ncol];
        u16* xw = Xbuf + (t & 1) * (32 * 72);
        #pragma unroll
        for (int r = 0; r < 4; ++r)
            xw[(wm + kq * 4 + r) * 72 + wn + lm] =
                f2bfu(fast_tanh(acc[r] + bia));
        __syncthreads();
        // re-read as phase-2 A-frags: row wm+lm, k-cols of this 64-chunk
        const u16* xr = Xbuf + (t & 1) * (32 * 72) + (size_t)(wm + lm) * 72;
        af2[2 * t + 0] = *(const short8*)(xr + kc);
        af2[2 * t + 1] = *(const short8*)(xr + 32 + kc);
    }

    // ---- phase 2: X2 tiles -> global (in place over P rows R0..R0+32)
    Wb = (const u16*)w2v; Wf = (const float*)w2v;
    #pragma unroll 1
    for (int t2 = 0; t2 < 8; ++t2) {
        const int n0 = t2 * 64;
        f32x4 acc = (f32x4){0.f, 0.f, 0.f, 0.f};
        KLOOP(af2)
        const int   ncol = n0 + wn + lm;
        const float bia  = ISBF ? bfu2f(b2b[ncol]) : b2f[ncol];
        #pragma unroll
        for (int r = 0; r < 4; ++r)
            P[(size_t)(R0 + wm + kq * 4 + r) * 512 + ncol] =
                f2bfu(fast_tanh(acc[r] + bia));
        __syncthreads();   // Bs reuse across t2 tiles
    }
#undef KLOOP
#undef STOREW
#undef FETCHW
}

__global__ __launch_bounds__(512, 2) void enc12_kernel(
    u16* __restrict__ P,
    const void* __restrict__ w1, const void* __restrict__ b1,
    const void* __restrict__ w2, const void* __restrict__ b2,
    const u16* __restrict__ Wdet, const unsigned int* __restrict__ Mdet)
{
    __shared__ __align__(16) u16 Bs[2 * 8704];       // 34.8 KB
    __shared__ __align__(16) u16 Xbuf[2 * 32 * 72];  //  9.2 KB
    __shared__ int s_flags;

    if (threadIdx.x < 64) {
        int fl = detect_wave(Wdet, Mdet, threadIdx.x);
        if (threadIdx.x == 0) s_flags = fl;
    }
    __syncthreads();
    if (s_flags & 1) enc12_body<true >(P, w1, b1, w2, b2, Bs, Xbuf);
    else             enc12_body<false>(P, w1, b1, w2, b2, Bs, Xbuf);
}

// ---------------------------------------------------------------------------
// Kernel 3: GEMM3 + logits.  H-tile = tanh([va|vb]@cw1 + cb1) kept in regs;
// logits = H @ cw2 + cb2 via shfl-reduce + f32 atomicAdd into zeroed out.
// Tile/stage structure byte-identical to r10's verified gemm_tile (128x64,
// 8 waves 4m x 2n, wave 32x32, BK=32 dbuf).  Grid 256: mb=bid&31, nb8=bid>>5.
// ---------------------------------------------------------------------------
template<bool ISBF>
__device__ __forceinline__ void g3_body(
    const u16* __restrict__ A, const u16* __restrict__ A2, const int K1,
    const void* __restrict__ Bv, const void* __restrict__ biasv,
    const void* __restrict__ w2v, const void* __restrict__ cb2v,
    float* __restrict__ outp, const int K,
    u16* __restrict__ As0, u16* __restrict__ Bs0)
{
    const int tid  = threadIdx.x;
    const int lane = tid & 63;
    const int wid = tid >> 6;
    const int wm  = (wid & 3) * 32;
    const int wn  = (wid >> 2) * 32;
    const int ar = tid >> 2;
    const int ak = (tid & 3) * 8;
    const int bk = tid >> 3;
    const int jn = tid & 7;
    const int nb = jn * 8;
    const int bofs = (((bk >> 3) + jn) & 3) * 8 + (bk & 7);
    const int lm = lane & 15;
    const int kq = lane >> 4;
    const int kc = kq * 8;
    const int m0 = (blockIdx.x & 31) * 128;
    const int n0 = (blockIdx.x >> 5) * 64;

    const u16*   Bb = (const u16*)Bv;
    const float* Bf = (const float*)Bv;

    f32x4 acc[2][2];
    #pragma unroll
    for (int i = 0; i < 2; ++i)
        #pragma unroll
        for (int j = 0; j < 2; ++j)
            acc[i][j] = (f32x4){0.f, 0.f, 0.f, 0.f};

    uint4 ra, rbb;
    float4 rf0, rf1;

#define FETCH(k0)                                                             \
    {                                                                         \
        const int kg = (k0) + ak;                                             \
        const u16* base = (kg < K1) ? (A + kg) : (A2 + (kg - K1));            \
        ra = *(const uint4*)(base + (size_t)(m0 + ar) * 512);                 \
        if (tid < 256) {                                                      \
            if constexpr (ISBF) {                                             \
                rbb = *(const uint4*)(Bb + (size_t)((k0) + bk) * 512 + n0 + nb);\
            } else {                                                          \
                const float* Bp = Bf + (size_t)((k0) + bk) * 512 + n0 + nb;   \
                rf0 = *(const float4*)(Bp + 0);                               \
                rf1 = *(const float4*)(Bp + 4);                               \
            }                                                                 \
        }                                                                     \
    }

#define STORE(pp)                                                             \
    {                                                                         \
        *(uint4*)&As0[(pp) * 5120 + ar * 40 + ak] = ra;                       \
        if (tid < 256) {                                                      \
            u16 bvals[8];                                                     \
            if constexpr (ISBF) {                                             \
                union { uint4 v; u16 s[8]; } ub; ub.v = rbb;                  \
                _Pragma("unroll")                                             \
                for (int i = 0; i < 8; ++i) bvals[i] = ub.s[i];               \
            } else {                                                          \
                bvals[0] = f2bfu(rf0.x); bvals[1] = f2bfu(rf0.y);             \
                bvals[2] = f2bfu(rf0.z); bvals[3] = f2bfu(rf0.w);             \
                bvals[4] = f2bfu(rf1.x); bvals[5] = f2bfu(rf1.y);             \
                bvals[6] = f2bfu(rf1.z); bvals[7] = f2bfu(rf1.w);             \
            }                                                                 \
            _Pragma("unroll")                                                 \
            for (int i = 0; i < 8; ++i)                                       \
                Bs0[(pp) * 2560 + (nb + i) * 40 + bofs] = bvals[i];           \
        }                                                                     \
    }

    FETCH(0)
    STORE(0)
    FETCH(32)
    __syncthreads();

    int p = 0;
    for (int k0 = 0; k0 < K; k0 += 32) {
        if (k0 + 32 < K) {
            STORE(p ^ 1)
            if (k0 + 64 < K) FETCH(k0 + 64)
        }
        const u16* Ap = As0 + p * 5120;
        const u16* Bp2 = Bs0 + p * 2560;
        short8 afr[2], bfr[2];
        #pragma unroll
        for (int i = 0; i < 2; ++i)
            afr[i] = *(const short8*)&Ap[(wm + i * 16 + lm) * 40 + kc];
        #pragma unroll
        for (int j = 0; j < 2; ++j) {
            const int n = wn + j * 16 + lm;
            const int ch = ((kq + (n >> 3)) & 3) * 8;
            bfr[j] = *(const short8*)&Bp2[n * 40 + ch];
        }
        #pragma unroll
        for (int i = 0; i < 2; ++i)
            #pragma unroll
            for (int j = 0; j < 2; ++j)
                acc[i][j] = __builtin_amdgcn_mfma_f32_16x16x32_bf16(
                    afr[i], bfr[j], acc[i][j], 0, 0, 0);
        if (k0 + 32 < K) __syncthreads();
        p ^= 1;
    }
#undef FETCH
#undef STORE

    // epilogue: H = tanh(acc + cb1[n]); logits partials; lm-reduce; atomics
    float lg[2][4][3];
    #pragma unroll
    for (int i = 0; i < 2; ++i)
        #pragma unroll
        for (int r = 0; r < 4; ++r)
            #pragma unroll
            for (int l = 0; l < 3; ++l) lg[i][r][l] = 0.f;

    #pragma unroll
    for (int j = 0; j < 2; ++j) {
        const int n = n0 + wn + j * 16 + lm;
        const float bsv = ISBF ? bfu2f(((const u16*)biasv)[n])
                               : ((const float*)biasv)[n];
        float wc[3];
        #pragma unroll
        for (int l = 0; l < 3; ++l)
            wc[l] = ISBF ? bfu2f(((const u16*)w2v)[n * 3 + l])
                         : ((const float*)w2v)[n * 3 + l];
        #pragma unroll
        for (int i = 0; i < 2; ++i)
            #pragma unroll
            for (int r = 0; r < 4; ++r) {
                const float h = fast_tanh(acc[i][j][r] + bsv);
                #pragma unroll
                for (int l = 0; l < 3; ++l) lg[i][r][l] += h * wc[l];
            }
    }
    // butterfly over the 16 lm lanes (lane bits 0..3)
    #pragma unroll
    for (int off = 1; off <= 8; off <<= 1)
        #pragma unroll
        for (int i = 0; i < 2; ++i)
            #pragma unroll
            for (int r = 0; r < 4; ++r)
                #pragma unroll
                for (int l = 0; l < 3; ++l)
                    lg[i][r][l] += __shfl_xor(lg[i][r][l], off);

    if (lm == 0) {
        const bool addb = (n0 == 0) && (wn == 0);   // exactly one per (m,l)
        float cb[3];
        #pragma unroll
        for (int l = 0; l < 3; ++l)
            cb[l] = ISBF ? bfu2f(((const u16*)cb2v)[l])
                         : ((const float*)cb2v)[l];
        #pragma unroll
        for (int i = 0; i < 2; ++i)
            #pragma unroll
            for (int r = 0; r < 4; ++r) {
                const int m = m0 + wm + i * 16 + kq * 4 + r;
                #pragma unroll
                for (int l = 0; l < 3; ++l) {
                    float v = lg[i][r][l];
                    if (addb) v += cb[l];
                    atomicAdd(&outp[m * 3 + l], v);
                }
            }
    }
}

__global__ __launch_bounds__(512, 2) void gemm3_logits(
    const u16* __restrict__ A, const u16* __restrict__ A2, int K1,
    const void* __restrict__ B, const void* __restrict__ bias,
    const void* __restrict__ w2, const void* __restrict__ cb2,
    float* __restrict__ out, int K,
    const u16* __restrict__ Wdet, const unsigned int* __restrict__ Mdet)
{
    __shared__ __align__(16) u16 As[2 * 128 * 40];
    __shared__ __align__(16) u16 Bs[2 * 64 * 40];
    __shared__ int s_flags;

    if (threadIdx.x < 64) {
        int fl = detect_wave(Wdet, Mdet, threadIdx.x);
        if (threadIdx.x == 0) s_flags = fl;
    }
    __syncthreads();
    if (s_flags & 1)
        g3_body<true >(A, A2, K1, B, bias, w2, cb2, out, K, As, Bs);
    else
        g3_body<false>(A, A2, K1, B, bias, w2, cb2, out, K, As, Bs);
}

// ---------------------------------------------------------------------------
extern "C" void kernel_launch(void* const* d_in, const int* in_sizes, int n_in,
                              void* d_out, int out_size, void* d_ws, size_t ws_size,
                              hipStream_t stream)
{
    const int* ids_a  = (const int*)d_in[0];
    const int* ids_b  = (const int*)d_in[1];
    const void* mask_a = d_in[2];
    const void* mask_b = d_in[3];
    const void* W_emb  = d_in[4];
    const void* enc_w1 = d_in[5];
    const void* enc_b1 = d_in[6];
    const void* enc_w2 = d_in[7];
    const void* enc_b2 = d_in[8];
    const void* cls_w1 = d_in[9];
    const void* cls_b1 = d_in[10];
    const void* cls_w2 = d_in[11];
    const void* cls_b2 = d_in[12];

    const u16* Wdet = (const u16*)W_emb;
    const unsigned int* Mdet = (const unsigned int*)mask_a;

    u16* buf0 = (u16*)d_ws;                          // 8192*512 bf16 = 8 MB
    float* outp = (float*)d_out;

    // logits accumulated via atomicAdd -> zero first (async, graph-safe)
    hipMemsetAsync(d_out, 0, 4096 * 3 * sizeof(float), stream);

    // P -> buf0 (rows 0..4095 side a, 4096..8191 side b)
    pool_kernel<<<8192, 128, 0, stream>>>(ids_a, ids_b, mask_a, mask_b,
                                          W_emb, buf0, Mdet);

    // X2 = tanh(tanh(P@w1+b1)@w2+b2), in place over buf0
    enc12_kernel<<<256, 512, 0, stream>>>(buf0, enc_w1, enc_b1,
                                          enc_w2, enc_b2, Wdet, Mdet);

    // logits = tanh([va|vb]@cw1+cb1) @ cw2 + cb2 -> d_out (f32, atomics)
    gemm3_logits<<<256, 512, 0, stream>>>(
        buf0, buf0 + (size_t)4096 * 512, 512, cls_w1, cls_b1,
        cls_w2, cls_b2, outp, 1024, Wdet, Mdet);
}